// Round 9
// baseline (19925.778 us; speedup 1.0000x reference)
//
#include <hip/hip_runtime.h>

#define NB 64
#define NT 1024
#define DIN 12
#define NH 256
#define NG 1024
#define NCLS 17
#define TCL 128
#define NCHUNK 8
#define XPS ((size_t)2 * NB * TCL * NG)   // floats per xp1 chunk buffer

#define B0ROW 288    // rec0 K: 256 h + 12 x + 1 one + 19 zero
#define B1ROW 256    // rec1 K: 256 h
#define A0PAD 296    // rec0 A row pad (halves)
#define A1PAD 264    // rec1 A row pad (halves)
#define GPAD  1034   // gates LDS row pad (f32): quad bank shift 8, 2-way max

typedef _Float16 f16;
typedef __attribute__((ext_vector_type(8))) _Float16 f16x8;
typedef __attribute__((ext_vector_type(4))) float f32x4;
typedef unsigned int uint;
typedef unsigned short ushort;

__device__ __forceinline__ float sigm(float v) { return 1.0f / (1.0f + __expf(-v)); }
__device__ __forceinline__ float tanh_(float v) {
    v = fminf(fmaxf(v, -15.0f), 15.0f);
    float e = __expf(2.0f * v);
    return (e - 1.0f) / (e + 1.0f);
}

// ---------------------------------------------------------------------------
// k_prep: Wb0 [2][1024][288] fp16 = [W_hh0 | W_ih0 | bias0 | 0]; Wb1
// [2][1024][256] fp16 = W_hh1; wih1h fp16 copy of w_ih1 (proj B operand);
// bsum1 = b_ih1 + b_hh1 (added by proj).
// ---------------------------------------------------------------------------
__global__ void k_prep(const float* __restrict__ w_hh0, const float* __restrict__ w_hh1,
                       const float* __restrict__ w_ih0, const float* __restrict__ w_ih1,
                       const float* __restrict__ b_ih0, const float* __restrict__ b_hh0,
                       const float* __restrict__ b_ih1, const float* __restrict__ b_hh1,
                       f16* __restrict__ Wb0, f16* __restrict__ Wb1,
                       f16* __restrict__ wih1h, float* __restrict__ bsum1) {
    int i = blockIdx.x * 256 + threadIdx.x;
    if (i < 2 * 1024 * B0ROW) {
        int k = i % B0ROW; int r = i / B0ROW;
        int g = r & 1023, dir = r >> 10;
        float v;
        if (k < 256)      v = w_hh0[((size_t)dir * 1024 + g) * 256 + k];
        else if (k < 268) v = w_ih0[((size_t)dir * 1024 + g) * 12 + (k - 256)];
        else if (k == 268) v = b_ih0[dir * 1024 + g] + b_hh0[dir * 1024 + g];
        else v = 0.f;
        Wb0[i] = (f16)v;
    }
    if (i < 2 * 1024 * B1ROW) {
        int k = i & 255; int r = i >> 8;
        int g = r & 1023, dir = r >> 10;
        Wb1[i] = (f16)w_hh1[((size_t)dir * 1024 + g) * 256 + k];
    }
    if (i < 2 * NG * 2 * NH) wih1h[i] = (f16)w_ih1[i];
    if (i < 2 * NG) bsum1[i] = b_ih1[i] + b_hh1[i];
}

// ---------------------------------------------------------------------------
// rec0_seq (round 9): MFMA-batched recurrence. Block = (dir, 16 batches),
// 512 threads = 8 waves; wave w owns gates [w*128, w*128+128).
// Per step: gates[16,1024] = A[16,288] @ Wb0[dir]^T via 16x16x32 f16 MFMA
// (A = [h | x_t | 1 | 0], so x-proj + bias ride in the K dim), then
// activation: lane (u=tid&255, hb=tid>>8) owns cells (u, batches hb*8+j).
// Fragment layouts identical to proj_role (verified in-kernel for rounds).
// ---------------------------------------------------------------------------
__device__ void rec0_seq(char* smem, int bid,
                         const f16* __restrict__ Wb0, const float* __restrict__ x,
                         f16* __restrict__ out0h) {
    f16* Ab = (f16*)smem;                             // [2 par][16][A0PAD]
    float* gb = (float*)(smem + 2 * 16 * A0PAD * 2);  // [16][GPAD]

    const int tid = threadIdx.x;
    const int w = tid >> 6, l = tid & 63;
    const int lane16 = l & 15, quad = l >> 4;
    const int dir = bid >> 2;
    const int B0 = (bid & 3) * 16;
    const int u = tid & 255, hb = tid >> 8;

    for (int n = tid; n < 2 * 16 * A0PAD; n += 512) Ab[n] = (f16)0.f;
    __syncthreads();
    if (tid < 32) {                                   // "1" column, both buffers
        int par = tid >> 4, b = tid & 15;
        Ab[(par * 16 + b) * A0PAD + 268] = (f16)1.f;
    }
    if (tid < 192) {                                  // x for step 0 -> A[0]
        int b = tid / 12, d = tid % 12;
        int t0 = dir ? NT - 1 : 0;
        Ab[(0 * 16 + b) * A0PAD + 256 + d] =
            (f16)x[((size_t)(B0 + b) * NT + t0) * DIN + d];
    }
    float cv[8];
    #pragma unroll
    for (int j = 0; j < 8; ++j) cv[j] = 0.f;
    __syncthreads();

    const f16* Bb = Wb0 + ((size_t)dir * 1024 + w * 128 + lane16) * B0ROW + quad * 8;

    #pragma unroll 1
    for (int it = 0; it < NT; ++it) {
        const int par = it & 1;
        const int t = dir ? (NT - 1 - it) : it;

        uint4 af[9];
        const f16* Arow = Ab + ((size_t)(par * 16 + lane16)) * A0PAD + quad * 8;
        #pragma unroll
        for (int kt = 0; kt < 9; ++kt) af[kt] = *(const uint4*)(Arow + kt * 32);

        f32x4 acc[8] = {};
        #pragma unroll
        for (int kt = 0; kt < 9; ++kt) {              // kt-outer: 8 indep chains
            f16x8 a = __builtin_bit_cast(f16x8, af[kt]);
            #pragma unroll
            for (int nt = 0; nt < 8; ++nt) {
                uint4 bv = *(const uint4*)(Bb + (size_t)nt * 16 * B0ROW + kt * 32);
                acc[nt] = __builtin_amdgcn_mfma_f32_16x16x32_f16(
                    a, __builtin_bit_cast(f16x8, bv), acc[nt], 0, 0, 0);
            }
        }
        #pragma unroll
        for (int nt = 0; nt < 8; ++nt) {
            int col = w * 128 + nt * 16 + lane16;
            #pragma unroll
            for (int reg = 0; reg < 4; ++reg)
                gb[(quad * 4 + reg) * GPAD + col] = acc[nt][reg];
        }
        __syncthreads();                              // gates visible

        // activation: 8 cells/lane; write h to out0h + next A buffer
        #pragma unroll
        for (int j = 0; j < 8; ++j) {
            int b = hb * 8 + j;
            float z0 = gb[b * GPAD + u];
            float z1 = gb[b * GPAD + 256 + u];
            float z2 = gb[b * GPAD + 512 + u];
            float z3 = gb[b * GPAD + 768 + u];
            cv[j] = sigm(z1) * cv[j] + sigm(z0) * tanh_(z2);
            float h = sigm(z3) * tanh_(cv[j]);
            f16 hh = (f16)h;
            out0h[((size_t)(B0 + b) * NT + t) * 512 + dir * 256 + u] = hh;
            Ab[((par ^ 1) * 16 + b) * A0PAD + u] = hh;
        }
        if (tid < 192) {                              // x for next step
            int b = tid / 12, d = tid % 12;
            int tn = (it + 1 < NT) ? (dir ? NT - 2 - it : it + 1) : t;
            Ab[((par ^ 1) * 16 + b) * A0PAD + 256 + d] =
                (f16)x[((size_t)(B0 + b) * NT + tn) * DIN + d];
        }
        __syncthreads();                              // next A ready
    }
}

// ---------------------------------------------------------------------------
// rec1_seq: same MFMA engine, K=256 (h only); xq (proj output incl. bias)
// loaded per step from xp1 (gate-major) and added at activation.
// ---------------------------------------------------------------------------
__device__ void rec1_seq(char* smem, int bid, int chunk,
                         const f16* __restrict__ Wb1, const float* __restrict__ xp1,
                         float* __restrict__ hst, float* __restrict__ cst,
                         float* __restrict__ hsm) {
    f16* Ab = (f16*)smem;                             // [2 par][16][A1PAD]
    float* gb = (float*)(smem + 2 * 16 * A1PAD * 2);  // [16][GPAD]

    const int tid = threadIdx.x;
    const int w = tid >> 6, l = tid & 63;
    const int lane16 = l & 15, quad = l >> 4;
    const int dir = bid >> 2;
    const int B0 = (bid & 3) * 16;
    const int u = tid & 255, hb = tid >> 8;
    const int ld = 2 + dir;

    for (int n = tid; n < 2 * 16 * A1PAD; n += 512) Ab[n] = (f16)0.f;
    float cv[8], hv[8], hsv[8];
    #pragma unroll
    for (int j = 0; j < 8; ++j) { cv[j] = 0.f; hv[j] = 0.f; hsv[j] = 0.f; }
    __syncthreads();
    if (chunk > 0) {
        #pragma unroll
        for (int j = 0; j < 8; ++j) {
            int B = B0 + hb * 8 + j;
            int sidx = (ld * NB + B) * NH + u;
            cv[j] = cst[sidx]; hv[j] = hst[sidx];
            hsv[j] = hsm[(dir * NB + B) * NH + u];
            Ab[(0 * 16 + hb * 8 + j) * A1PAD + u] = (f16)hv[j];
        }
    }
    __syncthreads();

    const f16* Bb = Wb1 + ((size_t)dir * 1024 + w * 128 + lane16) * B1ROW + quad * 8;

    #pragma unroll 1
    for (int it = 0; it < TCL; ++it) {
        const int par = it & 1;

        // xq loads (consumed post-barrier; latency hidden under MFMA)
        float xq[8][4];
        #pragma unroll
        for (int j = 0; j < 8; ++j) {
            int B = B0 + hb * 8 + j;
            const float* xr = xp1 + ((size_t)(dir * NB + B) * TCL + it) * NG;
            #pragma unroll
            for (int q = 0; q < 4; ++q) xq[j][q] = xr[q * 256 + u];
        }

        uint4 af[8];
        const f16* Arow = Ab + ((size_t)(par * 16 + lane16)) * A1PAD + quad * 8;
        #pragma unroll
        for (int kt = 0; kt < 8; ++kt) af[kt] = *(const uint4*)(Arow + kt * 32);

        f32x4 acc[8] = {};
        #pragma unroll
        for (int kt = 0; kt < 8; ++kt) {
            f16x8 a = __builtin_bit_cast(f16x8, af[kt]);
            #pragma unroll
            for (int nt = 0; nt < 8; ++nt) {
                uint4 bv = *(const uint4*)(Bb + (size_t)nt * 16 * B1ROW + kt * 32);
                acc[nt] = __builtin_amdgcn_mfma_f32_16x16x32_f16(
                    a, __builtin_bit_cast(f16x8, bv), acc[nt], 0, 0, 0);
            }
        }
        #pragma unroll
        for (int nt = 0; nt < 8; ++nt) {
            int col = w * 128 + nt * 16 + lane16;
            #pragma unroll
            for (int reg = 0; reg < 4; ++reg)
                gb[(quad * 4 + reg) * GPAD + col] = acc[nt][reg];
        }
        __syncthreads();                              // gates visible

        #pragma unroll
        for (int j = 0; j < 8; ++j) {
            int b = hb * 8 + j;
            float z0 = gb[b * GPAD + u]       + xq[j][0];
            float z1 = gb[b * GPAD + 256 + u] + xq[j][1];
            float z2 = gb[b * GPAD + 512 + u] + xq[j][2];
            float z3 = gb[b * GPAD + 768 + u] + xq[j][3];
            cv[j] = sigm(z1) * cv[j] + sigm(z0) * tanh_(z2);
            hv[j] = sigm(z3) * tanh_(cv[j]);
            hsv[j] += hv[j];
            Ab[((par ^ 1) * 16 + b) * A1PAD + u] = (f16)hv[j];
        }
        __syncthreads();                              // next A ready
    }

    #pragma unroll
    for (int j = 0; j < 8; ++j) {
        int B = B0 + hb * 8 + j;
        int sidx = (ld * NB + B) * NH + u;
        cst[sidx] = cv[j]; hst[sidx] = hv[j];
        hsm[(dir * NB + B) * NH + u] = hsv[j];
    }
}

// ---------------------------------------------------------------------------
// proj_role (chunk c): unchanged MFMA, but xp1 now GATE-MAJOR: [..][g]
// (so rec1's per-(q) activation reads coalesce across lanes u).
// ---------------------------------------------------------------------------
__device__ void proj_role(int pb, int c,
                          const f16* __restrict__ out0h, const f16* __restrict__ wih1h,
                          const float* __restrict__ bsum1, float* __restrict__ xp1) {
    const int tid = threadIdx.x;
    const int w = tid >> 6, l = tid & 63;
    const int lane16 = l & 15, quad = l >> 4;

    const int mtg = pb * 8 + w;                // 0..1023
    const int dirt = mtg >> 9;
    const int mtl = mtg & 511;

    const int ra = mtl * 16 + lane16;          // row over b(64) x tl(128)
    const int ab = ra >> 7, tla = ra & 127;
    const int ta = dirt ? (NT - 1 - c * TCL - tla) : (c * TCL + tla);
    const f16* Arow = out0h + ((size_t)ab * NT + ta) * 512 + quad * 8;

    uint4 afr[16];
    #pragma unroll
    for (int kt = 0; kt < 16; ++kt) afr[kt] = *(const uint4*)(Arow + kt * 32);

    int ob[4], otl[4];
    #pragma unroll
    for (int reg = 0; reg < 4; ++reg) {
        int rr = mtl * 16 + quad * 4 + reg;
        ob[reg] = rr >> 7; otl[reg] = rr & 127;
    }

    const f16* Bbase = wih1h + (size_t)dirt * NG * 512 + quad * 8;

    #pragma unroll 1
    for (int nt = 0; nt < 64; ++nt) {
        const int col = nt * 16 + lane16;
        const f16* Brow = Bbase + (size_t)col * 512;
        float bias = bsum1[dirt * NG + col];

        f32x4 acc = {0.f, 0.f, 0.f, 0.f};
        #pragma unroll
        for (int kt = 0; kt < 16; ++kt) {
            uint4 bv = *(const uint4*)(Brow + kt * 32);
            acc = __builtin_amdgcn_mfma_f32_16x16x32_f16(
                __builtin_bit_cast(f16x8, afr[kt]),
                __builtin_bit_cast(f16x8, bv), acc, 0, 0, 0);
        }
        #pragma unroll
        for (int reg = 0; reg < 4; ++reg) {
            xp1[((size_t)(dirt * NB + ob[reg]) * TCL + otl[reg]) * NG + col]
                = acc[reg] + bias;
        }
    }
}

// ---------------------------------------------------------------------------
// Phase A: layer 0. 8 blocks x 512 threads (2 dirs x 4 batch-groups).
// ---------------------------------------------------------------------------
__global__ __launch_bounds__(512)
__attribute__((amdgpu_waves_per_eu(2, 2)))
void k_rec0(const f16* __restrict__ Wb0, const float* __restrict__ x,
            f16* __restrict__ out0h) {
    extern __shared__ __align__(16) char smem[];
    rec0_seq(smem, blockIdx.x, Wb0, x, out0h);
}

// ---------------------------------------------------------------------------
// Phase B launch j: blocks 0..7 = rec1 chunk j-1; blocks 8..135 = proj
// chunk j. Double-buffered xp1.
// ---------------------------------------------------------------------------
__global__ __launch_bounds__(512)
__attribute__((amdgpu_waves_per_eu(2, 2)))
void k_pipe(int j,
            const f16* __restrict__ Wb1,
            const f16* __restrict__ out0h, const f16* __restrict__ wih1h,
            const float* __restrict__ bsum1, float* __restrict__ xp1,
            float* __restrict__ hst, float* __restrict__ cst,
            float* __restrict__ hsm) {
    extern __shared__ __align__(16) char smem[];
    const int bid = blockIdx.x;
    if (bid < 8) {
        const int cc = j - 1;
        if (cc >= 0 && cc < NCHUNK)
            rec1_seq(smem, bid, cc, Wb1,
                     xp1 + (size_t)(cc & 1) * XPS, hst, cst, hsm);
    } else {
        const int cp = j;
        if (cp < NCHUNK)
            proj_role(bid - 8, cp, out0h, wih1h, bsum1,
                      xp1 + (size_t)(cp & 1) * XPS);
    }
}

// ---------------------------------------------------------------------------
__global__ void k_fc(const float* __restrict__ hsm, const float* __restrict__ fc_w,
                     const float* __restrict__ fc_b, float* __restrict__ out) {
    const int b = blockIdx.x;
    const int n = threadIdx.x;
    if (n >= NCLS) return;
    float acc = fc_b[n];
    const float inv = 1.0f / (float)NT;
    for (int k = 0; k < 2 * NH; ++k) {
        float pv = hsm[((k >> 8) * NB + b) * NH + (k & 255)];
        acc += (pv * inv) * fc_w[n * 2 * NH + k];
    }
    out[b * NCLS + n] = acc;
}

// ---------------------------------------------------------------------------
extern "C" void kernel_launch(void* const* d_in, const int* in_sizes, int n_in,
                              void* d_out, int out_size, void* d_ws, size_t ws_size,
                              hipStream_t stream) {
    const float* x     = (const float*)d_in[0];
    const float* w_ih0 = (const float*)d_in[1];
    const float* w_hh0 = (const float*)d_in[2];
    const float* b_ih0 = (const float*)d_in[3];
    const float* b_hh0 = (const float*)d_in[4];
    const float* w_ih1 = (const float*)d_in[5];
    const float* w_hh1 = (const float*)d_in[6];
    const float* b_ih1 = (const float*)d_in[7];
    const float* b_hh1 = (const float*)d_in[8];
    const float* fc_w  = (const float*)d_in[9];
    const float* fc_b  = (const float*)d_in[10];
    float* out = (float*)d_out;

    char* ws = (char*)d_ws;
    f16* Wb0   = (f16*)ws;                         // 589824 h
    f16* Wb1   = Wb0 + 2 * 1024 * B0ROW;           // 524288 h
    f16* wih1h = Wb1 + 2 * 1024 * B1ROW;           // 1048576 h
    float* bsum1 = (float*)(wih1h + 2 * NG * 2 * NH);  // 2048 f
    float* hst  = bsum1 + 2048;                    // 65536 f
    float* cst  = hst + 65536;                     // 65536 f
    float* hsm  = cst + 65536;                     // 32768 f
    float* xp1  = hsm + 32768;                     // 2 x 16777216 f = 128 MB
    f16* out0h  = (f16*)(xp1 + 2 * XPS);           // 33554432 h = 64 MB

    k_prep<<<dim3(4096), dim3(256), 0, stream>>>(
        w_hh0, w_hh1, w_ih0, w_ih1, b_ih0, b_hh0, b_ih1, b_hh1,
        Wb0, Wb1, wih1h, bsum1);

    const int smem0 = 2 * 16 * A0PAD * 2 + 16 * GPAD * 4;  // 18944 + 66176
    const int smem1 = 2 * 16 * A1PAD * 2 + 16 * GPAD * 4;  // 16896 + 66176

    k_rec0<<<dim3(8), dim3(512), smem0, stream>>>(Wb0, x, out0h);

    for (int j = 0; j <= NCHUNK; ++j) {
        k_pipe<<<dim3(136), dim3(512), smem1, stream>>>(
            j, Wb1, out0h, wih1h, bsum1, xp1, hst, cst, hsm);
    }

    k_fc<<<dim3(64), dim3(32), 0, stream>>>(hsm, fc_w, fc_b, out);
}

// Round 10
// 5095.250 us; speedup vs baseline: 3.9107x; 3.9107x over previous
//
#include <hip/hip_runtime.h>

#define NB 64
#define NT 1024
#define DIN 12
#define NH 256
#define NG 1024
#define NCLS 17
#define TCL 128
#define NCHUNK 8
#define XPS ((size_t)2 * NB * TCL * NG)   // floats per xp1 chunk buffer

typedef _Float16 f16;
typedef __attribute__((ext_vector_type(2))) _Float16 half2_t;
typedef __attribute__((ext_vector_type(8))) _Float16 f16x8;
typedef __attribute__((ext_vector_type(4))) float f32x4;
typedef unsigned int uint;
typedef unsigned short ushort;

struct U4 { uint x, y, z, w; };

__device__ __forceinline__ float sigm(float v) { return 1.0f / (1.0f + __expf(-v)); }
__device__ __forceinline__ float tanh_(float v) {
    v = fminf(fmaxf(v, -15.0f), 15.0f);
    float e = __expf(2.0f * v);
    return (e - 1.0f) / (e + 1.0f);
}
__device__ __forceinline__ float dot2(uint w, uint h, float c) {
    return __builtin_amdgcn_fdot2(__builtin_bit_cast(half2_t, w),
                                  __builtin_bit_cast(half2_t, h), c, false);
}
__device__ __forceinline__ uint pack16(float a, float b) {
    union { f16 h[2]; uint u; } cv; cv.h[0] = (f16)a; cv.h[1] = (f16)b; return cv.u;
}
__device__ __forceinline__ uint pkrtz(float a, float b) {
    return __builtin_bit_cast(uint, __builtin_amdgcn_cvt_pkrtz(a, b));
}
__device__ __forceinline__ ushort hbits(f16 v) {
    union { f16 h; ushort u; } cv; cv.h = v; return cv.u;
}
__device__ __forceinline__ uint rdlane(uint v, int l) {
    return (uint)__builtin_amdgcn_readlane((int)v, l);
}

// ---------------------------------------------------------------------------
// Broadcast + dot machinery (comp-major over 8 accumulators).
// ---------------------------------------------------------------------------
#define RDL4(HV, G, S0, S1, S2, S3)                                           \
    uint S0 = rdlane((HV).x, (G)), S1 = rdlane((HV).y, (G)),                  \
         S2 = rdlane((HV).z, (G)), S3 = rdlane((HV).w, (G))

#define DOTS_GRP(AH, BH, W0, W1, W2, W3, S0, S1, S2, S3) do {                 \
    AH[0] = dot2((W0).x, (S0), AH[0]); AH[1] = dot2((W1).x, (S0), AH[1]);     \
    AH[2] = dot2((W2).x, (S0), AH[2]); AH[3] = dot2((W3).x, (S0), AH[3]);     \
    BH[0] = dot2((W0).y, (S1), BH[0]); BH[1] = dot2((W1).y, (S1), BH[1]);     \
    BH[2] = dot2((W2).y, (S1), BH[2]); BH[3] = dot2((W3).y, (S1), BH[3]);     \
    AH[0] = dot2((W0).z, (S2), AH[0]); AH[1] = dot2((W1).z, (S2), AH[1]);     \
    AH[2] = dot2((W2).z, (S2), AH[2]); AH[3] = dot2((W3).z, (S2), AH[3]);     \
    BH[0] = dot2((W0).w, (S3), BH[0]); BH[1] = dot2((W1).w, (S3), BH[1]);     \
    BH[2] = dot2((W2).w, (S3), BH[2]); BH[3] = dot2((W3).w, (S3), BH[3]);     \
} while (0)

// Loop-carried residency pin: non-volatile empty asm "+v". Emits ZERO
// instructions, but each iteration's value is an opaque function of the
// previous iteration's -> LLVM cannot rematerialize it by re-loading from
// memory (R4's one-shot pin failed exactly because re-load was legal).
#define PINC4(W) asm("" : "+v"((W).x), "+v"((W).y), "+v"((W).z), "+v"((W).w))

// ---------------------------------------------------------------------------
// k_prep: k-split packing (R4 layout, unchanged).
// Wk{0,1}n [dir][q][m 0..15][t512] uint4; lane t512=(u,kh) holds
// w_hh[dir][q*256+u][2*kp..2*kp+1] for kp = kh*64+4m+c, c=0..3.
// Per-lane group usage: m 0..5 VGPR-resident, m 6..11 streamed, m 12..15 LDS.
// ---------------------------------------------------------------------------
__global__ void k_prep(const float* __restrict__ w_hh0, const float* __restrict__ w_hh1,
                       const float* __restrict__ w_ih0, const float* __restrict__ w_ih1,
                       const float* __restrict__ b_ih1, const float* __restrict__ b_hh1,
                       uint* __restrict__ Wk0n, uint* __restrict__ wih0n,
                       uint* __restrict__ Wk1n,
                       f16* __restrict__ wih1h, float* __restrict__ bsum1) {
    int i = blockIdx.x * 256 + threadIdx.x;
    if (i < 262144) {                      // Wk0n
        int c = i & 3; int r = i >> 2;
        int t512 = r & 511; int s = r >> 9;
        int m = s & 15, q = (s >> 4) & 3, dir = s >> 6;
        int u = t512 & 255, kh = t512 >> 8;
        int kp = kh * 64 + 4 * m + c;
        const float* row = w_hh0 + (size_t)dir * NG * NH + (size_t)(q * 256 + u) * NH;
        Wk0n[i] = pack16(row[2 * kp], row[2 * kp + 1]);
    }
    if (i < 262144) {                      // Wk1n
        int c = i & 3; int r = i >> 2;
        int t512 = r & 511; int s = r >> 9;
        int m = s & 15, q = (s >> 4) & 3, dir = s >> 6;
        int u = t512 & 255, kh = t512 >> 8;
        int kp = kh * 64 + 4 * m + c;
        const float* row = w_hh1 + (size_t)dir * NG * NH + (size_t)(q * 256 + u) * NH;
        Wk1n[i] = pack16(row[2 * kp], row[2 * kp + 1]);
    }
    if (i < 12288) {                       // wih0n: [dir][g2*6+dp][t512]
        int t512 = i & 511; int r = i >> 9;
        int dp = r % 6, g2 = (r / 6) & 1, dir = r / 12;
        int q = 2 * (t512 >> 8) + g2, u = t512 & 255;
        const float* row = w_ih0 + ((size_t)dir * NG + q * 256 + u) * DIN;
        wih0n[i] = pack16(row[2 * dp], row[2 * dp + 1]);
    }
    if (i < 2 * NG * 2 * NH) wih1h[i] = (f16)w_ih1[i];
    if (i < 2 * NG) bsum1[i] = b_ih1[i] + b_hh1[i];
}

// ---------------------------------------------------------------------------
// rec0_seq (round 10): R4 structure (k-split, 512 thr, 2 waves/SIMD) with
// hybrid sourcing: 6 groups VGPR-RESIDENT (loop-carried pin, free), 6
// streamed from L2 in two 3-group batches interleaved with resident dots
// (latency cover), 4 in LDS. Stream traffic halves vs R4: 393->196 KB/CU/step.
// ---------------------------------------------------------------------------
__device__ void rec0_seq(char* smem, int rb,
                         const uint* __restrict__ Wk0n, const uint* __restrict__ wih0n,
                         const float* __restrict__ b_ih0, const float* __restrict__ b_hh0,
                         const float* __restrict__ x, f16* __restrict__ out0h,
                         float* __restrict__ hst, float* __restrict__ cst) {
    uint4* wlds4 = (uint4*)smem;                         // [4 q][4 mm][512] uint4 = 128 KB
    ushort* hs16 = (ushort*)(smem + 131072);             // [2 par][256] f16 = 1 KB
    float4* zb4  = (float4*)(smem + 132096);             // [256] float4 = 4 KB

    const int tid = threadIdx.x;
    const int dir = rb >> 6;
    const int b = rb & 63;
    const int u = tid & 255;
    const int kh = tid >> 8;
    const uint4* W4 = (const uint4*)Wk0n;

    #pragma unroll
    for (int q = 0; q < 4; ++q)
        #pragma unroll
        for (int mm = 0; mm < 4; ++mm)
            wlds4[(q * 4 + mm) * 512 + tid] =
                W4[((size_t)(dir * 4 + q) * 16 + 12 + mm) * 512 + tid];

    U4 wres[4][6];                          // groups m = 0..5, resident
    #pragma unroll
    for (int q = 0; q < 4; ++q)
        #pragma unroll
        for (int m = 0; m < 6; ++m) {
            uint4 t = W4[((size_t)(dir * 4 + q) * 16 + m) * 512 + tid];
            wres[q][m].x = t.x; wres[q][m].y = t.y;
            wres[q][m].z = t.z; wres[q][m].w = t.w;
        }

    uint wih[12];
    float bias2[2];
    #pragma unroll
    for (int g2 = 0; g2 < 2; ++g2) {
        const int q = 2 * kh + g2;
        bias2[g2] = b_ih0[dir * NG + q * 256 + u] + b_hh0[dir * NG + q * 256 + u];
        #pragma unroll
        for (int dp = 0; dp < 6; ++dp)
            wih[g2 * 6 + dp] = wih0n[(dir * 12 + g2 * 6 + dp) * 512 + tid];
    }

    const int sidx = (dir * NB + b) * NH + u;
    const int seg = kh * 16 + (tid & 15);
    const bool storer = (tid & 255) < 16;
    float cv = 0.f, hv = 0.f;
    if (tid < 256) hs16[tid] = 0;
    __syncthreads();

    #pragma unroll 1
    for (int it = 0; it < NT; ++it) {
        const int par = it & 1;
        uint4 hvv = ((const uint4*)(hs16 + par * 256))[seg];

        // loop-carried pin: zero instructions, forbids re-load of wres
        #pragma unroll
        for (int q = 0; q < 4; ++q)
            #pragma unroll
            for (int m = 0; m < 6; ++m) PINC4(wres[q][m]);

        // stream batch A (groups 6..8) — issue now, consume after cover
        uint4 stA[4][3];
        #pragma unroll
        for (int q = 0; q < 4; ++q)
            #pragma unroll
            for (int m = 0; m < 3; ++m)
                stA[q][m] = W4[((size_t)(dir * 4 + q) * 16 + 6 + m) * 512 + tid];

        // store h(it-1) to out0h from hvv (ack drains under the dot stream)
        if (it > 0 && storer) {
            const int tprev = dir ? (NT - it) : (it - 1);
            *(uint4*)(out0h + ((size_t)b * NT + tprev) * 512 + dir * 256 + seg * 8) = hvv;
        }

        // x-projection (VALU cover for hvv + stream-A latency)
        const int t = dir ? (NT - 1 - it) : it;
        const float4* xp = (const float4*)(x + ((size_t)b * NT + t) * DIN);
        float4 A = xp[0], B4 = xp[1], C4 = xp[2];
        uint xph[6] = {pkrtz(A.x, A.y), pkrtz(A.z, A.w), pkrtz(B4.x, B4.y),
                       pkrtz(B4.z, B4.w), pkrtz(C4.x, C4.y), pkrtz(C4.z, C4.w)};
        float xz0 = bias2[0], xz1 = bias2[1];
        #pragma unroll
        for (int d = 0; d < 6; ++d) {
            xz0 = dot2(wih[d], xph[d], xz0);
            xz1 = dot2(wih[6 + d], xph[d], xz1);
        }

        float ahA[4] = {0.f, 0.f, 0.f, 0.f};
        float ahB[4] = {0.f, 0.f, 0.f, 0.f};

        // resident groups 0..2 (more stream-A cover)
        #pragma unroll
        for (int m = 0; m < 3; ++m) {
            RDL4(hvv, m, s0, s1, s2, s3);
            DOTS_GRP(ahA, ahB, wres[0][m], wres[1][m], wres[2][m], wres[3][m],
                     s0, s1, s2, s3);
        }
        // consume stream A (h chunks 6..8)
        #pragma unroll
        for (int m = 0; m < 3; ++m) {
            RDL4(hvv, 6 + m, s0, s1, s2, s3);
            DOTS_GRP(ahA, ahB, stA[0][m], stA[1][m], stA[2][m], stA[3][m],
                     s0, s1, s2, s3);
        }
        // stream batch B (groups 9..11)
        uint4 stB[4][3];
        #pragma unroll
        for (int q = 0; q < 4; ++q)
            #pragma unroll
            for (int m = 0; m < 3; ++m)
                stB[q][m] = W4[((size_t)(dir * 4 + q) * 16 + 9 + m) * 512 + tid];
        // resident groups 3..5 (stream-B cover)
        #pragma unroll
        for (int m = 3; m < 6; ++m) {
            RDL4(hvv, m, s0, s1, s2, s3);
            DOTS_GRP(ahA, ahB, wres[0][m], wres[1][m], wres[2][m], wres[3][m],
                     s0, s1, s2, s3);
        }
        // consume stream B (h chunks 9..11)
        #pragma unroll
        for (int m = 0; m < 3; ++m) {
            RDL4(hvv, 9 + m, s0, s1, s2, s3);
            DOTS_GRP(ahA, ahB, stB[0][m], stB[1][m], stB[2][m], stB[3][m],
                     s0, s1, s2, s3);
        }
        // LDS groups (h chunks 12..15)
        #pragma unroll
        for (int gg = 0; gg < 4; ++gg) {
            uint4 l0 = wlds4[(0 * 4 + gg) * 512 + tid];
            uint4 l1 = wlds4[(1 * 4 + gg) * 512 + tid];
            uint4 l2 = wlds4[(2 * 4 + gg) * 512 + tid];
            uint4 l3 = wlds4[(3 * 4 + gg) * 512 + tid];
            RDL4(hvv, 12 + gg, s0, s1, s2, s3);
            DOTS_GRP(ahA, ahB, l0, l1, l2, l3, s0, s1, s2, s3);
        }

        float p0 = ahA[0] + ahB[0], p1 = ahA[1] + ahB[1];
        float p2 = ahA[2] + ahB[2], p3 = ahA[3] + ahB[3];
        if (kh == 0) { p0 += xz0; p1 += xz1; }   // kh uniform per wave
        else         { p2 += xz0; p3 += xz1; }

        if (kh) zb4[u] = (float4){p0, p1, p2, p3};
        __syncthreads();                          // A: partials visible
        if (!kh) {
            float4 zp = zb4[u];
            float z0 = p0 + zp.x, z1 = p1 + zp.y;
            float z2 = p2 + zp.z, z3 = p3 + zp.w;
            cv = sigm(z1) * cv + sigm(z0) * tanh_(z2);
            hv = sigm(z3) * tanh_(cv);
            hs16[(par ^ 1) * 256 + u] = hbits((f16)hv);
        }
        __syncthreads();                          // B: new h visible
    }

    // epilogue: store h(NT-1)
    if (storer) {
        uint4 hvf = ((const uint4*)(hs16 + 0 * 256))[seg];
        const int tlast = dir ? 0 : (NT - 1);
        *(uint4*)(out0h + ((size_t)b * NT + tlast) * 512 + dir * 256 + seg * 8) = hvf;
    }
    if (!kh) { cst[sidx] = cv; hst[sidx] = hv; }
}

// ---------------------------------------------------------------------------
// rec1_seq: hybrid twin (6 resident + 6 streamed + 4 LDS); xq prefetch one
// step ahead by kh=0 waves.
// ---------------------------------------------------------------------------
__device__ void rec1_seq(char* smem, int rb, int chunk, int nsteps,
                         const uint* __restrict__ Wk1n, const float* __restrict__ xp1,
                         float* __restrict__ hst, float* __restrict__ cst,
                         float* __restrict__ hsm) {
    uint4* wlds4 = (uint4*)smem;                         // 128 KB
    ushort* hs16 = (ushort*)(smem + 131072);             // 1 KB
    float4* zb4  = (float4*)(smem + 132096);             // 4 KB

    const int tid = threadIdx.x;
    const int dir = rb >> 6;
    const int b = rb & 63;
    const int u = tid & 255;
    const int kh = tid >> 8;
    const int ld = 2 + dir;
    const uint4* W4 = (const uint4*)Wk1n;

    #pragma unroll
    for (int q = 0; q < 4; ++q)
        #pragma unroll
        for (int mm = 0; mm < 4; ++mm)
            wlds4[(q * 4 + mm) * 512 + tid] =
                W4[((size_t)(dir * 4 + q) * 16 + 12 + mm) * 512 + tid];

    U4 wres[4][6];
    #pragma unroll
    for (int q = 0; q < 4; ++q)
        #pragma unroll
        for (int m = 0; m < 6; ++m) {
            uint4 t = W4[((size_t)(dir * 4 + q) * 16 + m) * 512 + tid];
            wres[q][m].x = t.x; wres[q][m].y = t.y;
            wres[q][m].z = t.z; wres[q][m].w = t.w;
        }

    const int sidx = (ld * NB + b) * NH + u;
    const int seg = kh * 16 + (tid & 15);
    float cv = 0.f, hv = 0.f, hsv = 0.f;
    if (chunk > 0 && !kh) {
        cv = cst[sidx]; hv = hst[sidx];
        hsv = hsm[(dir * NB + b) * NH + u];
    }
    if (tid < 256) hs16[tid] = hbits((f16)hv);

    const float* xbase = xp1 + ((size_t)dir * NB + b) * TCL * NG + u * 4;
    float4 xq_cur = {0.f, 0.f, 0.f, 0.f};
    if (!kh) xq_cur = *(const float4*)xbase;
    __syncthreads();

    #pragma unroll 1
    for (int it = 0; it < nsteps; ++it) {
        const int par = it & 1;
        uint4 hvv = ((const uint4*)(hs16 + par * 256))[seg];

        #pragma unroll
        for (int q = 0; q < 4; ++q)
            #pragma unroll
            for (int m = 0; m < 6; ++m) PINC4(wres[q][m]);

        // stream batch A (groups 6..8)
        uint4 stA[4][3];
        #pragma unroll
        for (int q = 0; q < 4; ++q)
            #pragma unroll
            for (int m = 0; m < 3; ++m)
                stA[q][m] = W4[((size_t)(dir * 4 + q) * 16 + 6 + m) * 512 + tid];

        // prefetch next step's gate inputs
        float4 xq_nxt = xq_cur;
        if (!kh) {
            const int itn = (it + 1 < nsteps) ? (it + 1) : it;
            xq_nxt = *(const float4*)(xbase + (size_t)itn * NG);
        }

        float ahA[4] = {0.f, 0.f, 0.f, 0.f};
        float ahB[4] = {0.f, 0.f, 0.f, 0.f};

        #pragma unroll
        for (int m = 0; m < 3; ++m) {
            RDL4(hvv, m, s0, s1, s2, s3);
            DOTS_GRP(ahA, ahB, wres[0][m], wres[1][m], wres[2][m], wres[3][m],
                     s0, s1, s2, s3);
        }
        #pragma unroll
        for (int m = 0; m < 3; ++m) {
            RDL4(hvv, 6 + m, s0, s1, s2, s3);
            DOTS_GRP(ahA, ahB, stA[0][m], stA[1][m], stA[2][m], stA[3][m],
                     s0, s1, s2, s3);
        }
        uint4 stB[4][3];
        #pragma unroll
        for (int q = 0; q < 4; ++q)
            #pragma unroll
            for (int m = 0; m < 3; ++m)
                stB[q][m] = W4[((size_t)(dir * 4 + q) * 16 + 9 + m) * 512 + tid];
        #pragma unroll
        for (int m = 3; m < 6; ++m) {
            RDL4(hvv, m, s0, s1, s2, s3);
            DOTS_GRP(ahA, ahB, wres[0][m], wres[1][m], wres[2][m], wres[3][m],
                     s0, s1, s2, s3);
        }
        #pragma unroll
        for (int m = 0; m < 3; ++m) {
            RDL4(hvv, 9 + m, s0, s1, s2, s3);
            DOTS_GRP(ahA, ahB, stB[0][m], stB[1][m], stB[2][m], stB[3][m],
                     s0, s1, s2, s3);
        }
        #pragma unroll
        for (int gg = 0; gg < 4; ++gg) {
            uint4 l0 = wlds4[(0 * 4 + gg) * 512 + tid];
            uint4 l1 = wlds4[(1 * 4 + gg) * 512 + tid];
            uint4 l2 = wlds4[(2 * 4 + gg) * 512 + tid];
            uint4 l3 = wlds4[(3 * 4 + gg) * 512 + tid];
            RDL4(hvv, 12 + gg, s0, s1, s2, s3);
            DOTS_GRP(ahA, ahB, l0, l1, l2, l3, s0, s1, s2, s3);
        }

        float p0 = ahA[0] + ahB[0], p1 = ahA[1] + ahB[1];
        float p2 = ahA[2] + ahB[2], p3 = ahA[3] + ahB[3];
        if (!kh) { p0 += xq_cur.x; p1 += xq_cur.y; p2 += xq_cur.z; p3 += xq_cur.w; }

        if (kh) zb4[u] = (float4){p0, p1, p2, p3};
        __syncthreads();                          // A: partials visible
        if (!kh) {
            float4 zp = zb4[u];
            float z0 = p0 + zp.x, z1 = p1 + zp.y;
            float z2 = p2 + zp.z, z3 = p3 + zp.w;
            cv = sigm(z1) * cv + sigm(z0) * tanh_(z2);
            hv = sigm(z3) * tanh_(cv);
            hsv += hv;
            hs16[(par ^ 1) * 256 + u] = hbits((f16)hv);
        }
        __syncthreads();                          // B: new h visible
        xq_cur = xq_nxt;
    }

    if (!kh) {
        cst[sidx] = cv; hst[sidx] = hv;
        hsm[(dir * NB + b) * NH + u] = hsv;
    }
}

// ---------------------------------------------------------------------------
// proj_role (chunk c): fp16 MFMA 16x16x32 direct-from-global. 512-thread
// blocks: 8 waves, each wave handles 1 m-tile. (R4 verbatim)
// ---------------------------------------------------------------------------
__device__ void proj_role(int pb, int c,
                          const f16* __restrict__ out0h, const f16* __restrict__ wih1h,
                          const float* __restrict__ bsum1, float* __restrict__ xp1) {
    const int tid = threadIdx.x;
    const int w = tid >> 6, l = tid & 63;
    const int lane16 = l & 15, quad = l >> 4;

    const int mtg = pb * 8 + w;                // 0..1023
    const int dirt = mtg >> 9;
    const int mtl = mtg & 511;

    const int ra = mtl * 16 + lane16;          // row over b(64) x tl(128)
    const int ab = ra >> 7, tla = ra & 127;
    const int ta = dirt ? (NT - 1 - c * TCL - tla) : (c * TCL + tla);
    const f16* Arow = out0h + ((size_t)ab * NT + ta) * 512 + quad * 8;

    uint4 afr[16];
    #pragma unroll
    for (int kt = 0; kt < 16; ++kt) afr[kt] = *(const uint4*)(Arow + kt * 32);

    int ob[4], otl[4];
    #pragma unroll
    for (int reg = 0; reg < 4; ++reg) {
        int rr = mtl * 16 + quad * 4 + reg;
        ob[reg] = rr >> 7; otl[reg] = rr & 127;
    }

    const f16* Bbase = wih1h + (size_t)dirt * NG * 512 + quad * 8;

    #pragma unroll 1
    for (int nt = 0; nt < 64; ++nt) {
        const int col = nt * 16 + lane16;
        const f16* Brow = Bbase + (size_t)col * 512;
        float bias = bsum1[dirt * NG + col];

        f32x4 acc = {0.f, 0.f, 0.f, 0.f};
        #pragma unroll
        for (int kt = 0; kt < 16; ++kt) {
            uint4 bv = *(const uint4*)(Brow + kt * 32);
            acc = __builtin_amdgcn_mfma_f32_16x16x32_f16(
                __builtin_bit_cast(f16x8, afr[kt]),
                __builtin_bit_cast(f16x8, bv), acc, 0, 0, 0);
        }
        const int ucol = col & 255, qcol = col >> 8;
        #pragma unroll
        for (int reg = 0; reg < 4; ++reg) {
            xp1[((size_t)(dirt * NB + ob[reg]) * TCL + otl[reg]) * NG
                + ucol * 4 + qcol] = acc[reg] + bias;
        }
    }
}

// ---------------------------------------------------------------------------
// Phase A: layer 0. 128 blocks x 512 threads.
// ---------------------------------------------------------------------------
__global__ __launch_bounds__(512)
__attribute__((amdgpu_waves_per_eu(2, 2)))
void k_rec0(
    const uint* __restrict__ Wk0n, const uint* __restrict__ wih0n,
    const float* __restrict__ b_ih0, const float* __restrict__ b_hh0,
    const float* __restrict__ x, f16* __restrict__ out0h,
    float* __restrict__ hst, float* __restrict__ cst) {
    extern __shared__ __align__(16) char smem[];
    rec0_seq(smem, blockIdx.x, Wk0n, wih0n, b_ih0, b_hh0, x, out0h, hst, cst);
}

// ---------------------------------------------------------------------------
// Phase B launch j: blocks 0..127 = rec1 chunk j-1; blocks 128..255 = proj
// chunk j.
// ---------------------------------------------------------------------------
__global__ __launch_bounds__(512)
__attribute__((amdgpu_waves_per_eu(2, 2)))
void k_pipe(
    int j,
    const uint* __restrict__ Wk1n,
    const f16* __restrict__ out0h, const f16* __restrict__ wih1h,
    const float* __restrict__ bsum1, float* __restrict__ xp1,
    float* __restrict__ hst, float* __restrict__ cst, float* __restrict__ hsm) {
    extern __shared__ __align__(16) char smem[];
    const int bid = blockIdx.x;
    if (bid < 128) {
        const int cc = j - 1;
        if (cc >= 0 && cc < NCHUNK)
            rec1_seq(smem, bid, cc, TCL, Wk1n,
                     xp1 + (size_t)(cc & 1) * XPS, hst, cst, hsm);
    } else {
        const int cp = j;
        if (cp < NCHUNK)
            proj_role(bid - 128, cp, out0h, wih1h, bsum1,
                      xp1 + (size_t)(cp & 1) * XPS);
    }
}

// ---------------------------------------------------------------------------
__global__ void k_fc(const float* __restrict__ hsm, const float* __restrict__ fc_w,
                     const float* __restrict__ fc_b, float* __restrict__ out) {
    const int b = blockIdx.x;
    const int n = threadIdx.x;
    if (n >= NCLS) return;
    float acc = fc_b[n];
    const float inv = 1.0f / (float)NT;
    for (int k = 0; k < 2 * NH; ++k) {
        float pv = hsm[((k >> 8) * NB + b) * NH + (k & 255)];
        acc += (pv * inv) * fc_w[n * 2 * NH + k];
    }
    out[b * NCLS + n] = acc;
}

// ---------------------------------------------------------------------------
extern "C" void kernel_launch(void* const* d_in, const int* in_sizes, int n_in,
                              void* d_out, int out_size, void* d_ws, size_t ws_size,
                              hipStream_t stream) {
    const float* x     = (const float*)d_in[0];
    const float* w_ih0 = (const float*)d_in[1];
    const float* w_hh0 = (const float*)d_in[2];
    const float* b_ih0 = (const float*)d_in[3];
    const float* b_hh0 = (const float*)d_in[4];
    const float* w_ih1 = (const float*)d_in[5];
    const float* w_hh1 = (const float*)d_in[6];
    const float* b_ih1 = (const float*)d_in[7];
    const float* b_hh1 = (const float*)d_in[8];
    const float* fc_w  = (const float*)d_in[9];
    const float* fc_b  = (const float*)d_in[10];
    float* out = (float*)d_out;

    char* ws = (char*)d_ws;
    uint* Wk0n  = (uint*)ws;                      // 262144 u
    uint* wih0n = Wk0n + 262144;                  // 12288 u
    uint* Wk1n  = wih0n + 12288;                  // 262144 u
    f16* wih1h  = (f16*)(Wk1n + 262144);          // 1048576 h = 2 MB
    float* bsum1 = (float*)(wih1h + 1048576);     // 2048 f
    float* hst  = bsum1 + 2048;                   // 65536 f
    float* cst  = hst + 65536;                    // 65536 f
    float* hsm  = cst + 65536;                    // 32768 f
    float* xp1  = hsm + 32768;                    // 2 x 16777216 f = 128 MB
    f16* out0h  = (f16*)(xp1 + 2 * XPS);          // 33554432 h = 64 MB

    k_prep<<<dim3(4096), dim3(256), 0, stream>>>(
        w_hh0, w_hh1, w_ih0, w_ih1, b_ih1, b_hh1,
        Wk0n, wih0n, Wk1n, wih1h, bsum1);

    k_rec0<<<dim3(128), dim3(512), 136192, stream>>>(
        Wk0n, wih0n, b_ih0, b_hh0, x, out0h, hst, cst);

    for (int j = 0; j <= NCHUNK; ++j) {
        k_pipe<<<dim3(256), dim3(512), 136192, stream>>>(
            j, Wk1n, out0h, wih1h, bsum1, xp1, hst, cst, hsm);
    }

    k_fc<<<dim3(64), dim3(32), 0, stream>>>(hsm, fc_w, fc_b, out);
}